// Round 18
// baseline (160.404 us; speedup 1.0000x reference)
//
#include <hip/hip_runtime.h>
#include <hip/hip_bf16.h>

typedef unsigned short u16;
typedef unsigned int u32;
typedef __attribute__((ext_vector_type(8))) short s16x8;
typedef __attribute__((ext_vector_type(4))) float f32x4;
typedef __attribute__((ext_vector_type(16))) float f32x16;
typedef __attribute__((ext_vector_type(4))) u16 u16x4;

#define SLEN 2048
#define DMODEL 1024
#define NHEAD 16
#define DHEAD 64
#define LDQK 2048
#define VSTRIDE 4096
#define LOG2E 1.4426950408889634f

__device__ __forceinline__ u16 f2bf(float f) {
  union { __hip_bfloat16 h; u16 u; } c;
  c.h = __float2bfloat16(f);
  return c.u;
}

__device__ __forceinline__ u32 pk2(float a, float b) {
  union { __hip_bfloat162 h2; u32 u; } c;
  float2 f2; f2.x = a; f2.y = b;
  c.h2 = __float22bfloat162_rn(f2);
  return c.u;
}

__device__ __forceinline__ void gload_lds16(const u16* gsrc, u16* lds) {
  __builtin_amdgcn_global_load_lds((const __attribute__((address_space(1))) void*)gsrc,
                                   (__attribute__((address_space(3))) void*)lds, 16, 0, 0);
}

// Build PV A-fragment from 8 P values. v_permlane32_swap_b32 D,S swaps
// D[32:63] <-> S[0:31]. swap(A0,A2)/swap(A1,A3) reproduces the r4-verified
// shfl mapping in 2 ops (r14-verified: absmax unchanged, attn -5us).
__device__ __forceinline__ s16x8 make_pa(const float* p) {
  u32 A0 = pk2(p[0], p[1]), A1 = pk2(p[2], p[3]);
  u32 A2 = pk2(p[4], p[5]), A3 = pk2(p[6], p[7]);
  asm("v_permlane32_swap_b32 %0, %1" : "+v"(A0), "+v"(A2));
  asm("v_permlane32_swap_b32 %0, %1" : "+v"(A1), "+v"(A3));
  union { u32 w[4]; s16x8 v; } pw;
  pw.w[0] = A0; pw.w[1] = A1; pw.w[2] = A2; pw.w[3] = A3;
  return pw.v;
}

// ---------------- LayerNorm body (shared) ----------------
__device__ __forceinline__ void ln_body(
    int row, int t, const float* __restrict__ xa,
    const float* __restrict__ g, const float* __restrict__ bb,
    u16* __restrict__ outb) {
  const size_t base = (size_t)row * DMODEL;
  float4 v = *((const float4*)(xa + base) + t);
  float s1 = v.x + v.y + v.z + v.w;
  float s2 = v.x * v.x + v.y * v.y + v.z * v.z + v.w * v.w;
#pragma unroll
  for (int d = 1; d < 64; d <<= 1) { s1 += __shfl_xor(s1, d); s2 += __shfl_xor(s2, d); }
  __shared__ float red[8];
  if ((t & 63) == 0) { red[(t >> 6) * 2] = s1; red[(t >> 6) * 2 + 1] = s2; }
  __syncthreads();
  s1 = red[0] + red[2] + red[4] + red[6];
  s2 = red[1] + red[3] + red[5] + red[7];
  const float mu = s1 * (1.0f / 1024.0f);
  const float var = s2 * (1.0f / 1024.0f) - mu * mu;
  const float rs = rsqrtf(var + 1e-6f);
  const int c = t * 4;
  float o0 = (v.x - mu) * rs * g[c + 0] + bb[c + 0];
  float o1 = (v.y - mu) * rs * g[c + 1] + bb[c + 1];
  float o2 = (v.z - mu) * rs * g[c + 2] + bb[c + 2];
  float o3 = (v.w - mu) * rs * g[c + 3] + bb[c + 3];
  u16x4 o = { f2bf(o0), f2bf(o1), f2bf(o2), f2bf(o3) };
  *((u16x4*)(outb + base) + t) = o;
}

// ---------------- fused: weight convert (blocks 0..4095) + LN1 (blocks 4096..8191) ----------------
__global__ __launch_bounds__(256) void prep_kernel(
    const float* __restrict__ x,
    const float* __restrict__ Wq, const float* __restrict__ Wk, const float* __restrict__ Wv,
    const float* __restrict__ Wo, const float* __restrict__ bq, const float* __restrict__ bk,
    const float* __restrict__ bv, const float* __restrict__ mask,
    const float* __restrict__ g1, const float* __restrict__ b1,
    u16* __restrict__ Wqkv, u16* __restrict__ Wob, float* __restrict__ bias_qkv,
    float* __restrict__ am, u32* __restrict__ amflag, u16* __restrict__ h_bf) {
  const int bid = blockIdx.x;
  if (bid >= 4096) {
    ln_body(bid - 4096, threadIdx.x, x, g1, b1, h_bf);
    return;
  }
  const int t = bid * 256 + threadIdx.x;
  float4 v;
  u16* dst;
  if (t < 786432) {
    const int idx = t * 4;
    const int sec = idx >> 20;
    const int off = idx & 1048575;
    const float* src = (sec == 0) ? Wq : (sec == 1) ? Wk : Wv;
    v = *(const float4*)(src + off);
    dst = Wqkv + idx;
  } else {
    const int idx = (t - 786432) * 4;
    v = *(const float4*)(Wo + idx);
    dst = Wob + idx;
  }
  u16x4 o = { f2bf(v.x), f2bf(v.y), f2bf(v.z), f2bf(v.w) };
  *(u16x4*)dst = o;
  if (t < 768) {
    const int idx = t * 4;
    const int sec = idx >> 10;
    const int off = idx & 1023;
    const float* src = (sec == 0) ? bq : (sec == 1) ? bk : bv;
    *(float4*)(bias_qkv + idx) = *(const float4*)(src + off);
  }
  if (t < 1024) {
    const int idx = t * 4;
    float4 mk = *(const float4*)(mask + idx);
    const float C = -1e30f * LOG2E;
    float4 o2 = { (1.f - mk.x) * C, (1.f - mk.y) * C,
                  (1.f - mk.z) * C, (1.f - mk.w) * C };
    *(float4*)(am + idx) = o2;
  }
  if (t < 64) {
    const int bb = t >> 5, tile = t & 31;
    u32 fl = 0;
    for (int j = 0; j < 64; ++j)
      fl |= (mask[bb * SLEN + tile * 64 + j] != 1.0f) ? 1u : 0u;
    amflag[t] = fl;
  }
}

// ---------------- plain LN kernel (post-attention) ----------------
__global__ __launch_bounds__(256) void ln_kernel(
    const float* __restrict__ xa, const float* __restrict__ g,
    const float* __restrict__ bb, u16* __restrict__ outb) {
  ln_body(blockIdx.x, threadIdx.x, xa, g, bb, outb);
}

// ---------------- GEMM core (r13-proven): BK=64, single-stage, 32 MFMAs/barrier ----------------
__device__ __forceinline__ void gemm_core(
    const u16* __restrict__ A, const u16* __restrict__ B,
    const float* __restrict__ bias, const float* __restrict__ res,
    u16* __restrict__ outb, float* __restrict__ outf,
    int M, int N, int K, int m0, int n0, int mode,
    u16* As, u16* Bs) {
  const int t = threadIdx.x;
  const int l = t & 63, w = t >> 6, lr = l & 15, lg = l >> 4;
  const int wm = w >> 1, wn = w & 1;

  const f32x4 z4 = {0.f, 0.f, 0.f, 0.f};
  f32x4 acc[4][4];
#pragma unroll
  for (int i = 0; i < 4; ++i)
#pragma unroll
    for (int j = 0; j < 4; ++j) acc[i][j] = z4;

  for (int kt = 0; kt < K; kt += 64) {
#pragma unroll
    for (int p = 0; p < 4; ++p) {
      const int idx = p * 256 + t;
      const int row = idx >> 3;
      const int blk = idx & 7;
      const int sb = blk ^ (row & 7);
      gload_lds16(A + (size_t)(m0 + row) * K + kt + sb * 8, &As[idx * 8]);
      gload_lds16(B + (size_t)(n0 + row) * K + kt + sb * 8, &Bs[idx * 8]);
    }
    asm volatile("s_waitcnt vmcnt(0)" ::: "memory");
    __syncthreads();

#pragma unroll
    for (int ks = 0; ks < 2; ++ks) {
      s16x8 af[4], bfr[4];
#pragma unroll
      for (int mi = 0; mi < 4; ++mi) {
        const int row = wm * 64 + mi * 16 + lr;
        af[mi] = *(const s16x8*)&As[row * 64 + (((ks * 4 + lg) ^ (row & 7)) & 7) * 8];
      }
#pragma unroll
      for (int ni = 0; ni < 4; ++ni) {
        const int row = wn * 64 + ni * 16 + lr;
        bfr[ni] = *(const s16x8*)&Bs[row * 64 + (((ks * 4 + lg) ^ (row & 7)) & 7) * 8];
      }
#pragma unroll
      for (int mi = 0; mi < 4; ++mi)
#pragma unroll
        for (int ni = 0; ni < 4; ++ni)
          acc[mi][ni] = __builtin_amdgcn_mfma_f32_16x16x32_bf16(af[mi], bfr[ni], acc[mi][ni], 0, 0, 0);
    }
    __syncthreads();
  }

#pragma unroll
  for (int mi = 0; mi < 4; ++mi)
#pragma unroll
    for (int ni = 0; ni < 4; ++ni) {
      const int col = n0 + wn * 64 + ni * 16 + lr;
#pragma unroll
      for (int r = 0; r < 4; ++r) {
        const int rowb = m0 + wm * 64 + mi * 16 + lg * 4 + r;
        float vv = acc[mi][ni][r];
        if (mode == 2) {
          vv += bias[rowb];
          outb[(size_t)rowb * N + col] = f2bf(vv);
        } else if (mode == 0) {
          vv += bias[col];
          if (col < 1024) vv *= 0.125f * LOG2E;
          outb[(size_t)rowb * N + col] = f2bf(vv);
        } else {
          vv += bias[col] + res[(size_t)rowb * N + col];
          outf[(size_t)rowb * N + col] = vv;
        }
      }
    }
}

// fused QK-proj (lids 0..511) + V^T-proj (lids 512..767), XCD-chunked
__global__ __launch_bounds__(256) void qkv_gemm_kernel(
    const u16* __restrict__ h_bf, const u16* __restrict__ Wqkv,
    const float* __restrict__ biasq, u16* __restrict__ qkbuf, u16* __restrict__ vT) {
  __shared__ __align__(16) u16 As[128 * 64];
  __shared__ __align__(16) u16 Bs[128 * 64];
  const int bid = blockIdx.x;
  const int lid = (bid & 7) * 96 + (bid >> 3);   // 768 = 8 * 96, bijective
  if (lid < 512) {
    gemm_core(h_bf, Wqkv, biasq, nullptr, qkbuf, nullptr,
              4096, 2048, 1024, (lid & 31) * 128, (lid >> 5) * 128, 0, As, Bs);
  } else {
    const int id = lid - 512;
    gemm_core(Wqkv + (size_t)2048 * 1024, h_bf, biasq + 2048, nullptr, vT, nullptr,
              1024, 4096, 1024, (id & 7) * 128, (id >> 3) * 128, 2, As, Bs);
  }
}

// output projection with fused residual, XCD-chunked (grid 256)
__global__ __launch_bounds__(256) void out_gemm_kernel(
    const u16* __restrict__ h2, const u16* __restrict__ Wob,
    const float* __restrict__ bo, const float* __restrict__ res,
    float* __restrict__ outf) {
  __shared__ __align__(16) u16 As[128 * 64];
  __shared__ __align__(16) u16 Bs[128 * 64];
  const int bid = blockIdx.x;
  const int lid = (bid & 7) * 32 + (bid >> 3);   // 256 = 8 * 32, bijective
  gemm_core(h2, Wob, bo, res, nullptr, outf,
            4096, 1024, 1024, (lid & 31) * 128, (lid >> 5) * 128, 1, As, Bs);
}

// ---------------- flash attention, fixed-max softmax; epilogue adds x (residual) ----------------
// grid: 512 blocks x 256 thr (4 waves); wave owns 32 q rows; KV tile = 64.
// 4 LDS buffers, 2-tile-ahead staging, counted vmcnt(4) + raw s_barrier per tile
// (no per-tile full drain); kt-loop unrolled x4 with compile-time buffer indices.
__global__ __launch_bounds__(256) void attn_kernel(
    const u16* __restrict__ qk, const u16* __restrict__ vt,
    const float* __restrict__ am, const u32* __restrict__ amflag,
    const float* __restrict__ x, float* __restrict__ out) {
  const int did = blockIdx.x;
  const int lid = (did & 7) * 64 + (did >> 3);   // XCD-chunked (512 % 8 == 0)
  const int qb = lid & 15;
  const int h = (lid >> 4) & 15;
  const int b = lid >> 8;

  const int t = threadIdx.x;
  const int l = t & 63, w = t >> 6;
  const int l31 = l & 31;
  const int hi = l >> 5;
  const int hi4 = hi * 4;
  const int sw = l31 & 7;

  __shared__ __align__(16) u16 Ks[4][64 * 64];
  __shared__ __align__(16) u16 Vs[4][64 * 64];
  __shared__ float bcastS[4][32];

  const int q0 = qb * 128 + w * 32;

  const u16* qrow = qk + (size_t)(b * SLEN + q0 + l31) * LDQK + h * DHEAD + hi * 8;
  s16x8 qf[4];
#pragma unroll
  for (int f = 0; f < 4; ++f) qf[f] = *(const s16x8*)(qrow + f * 16);

  // per-wave 32-bit tile-flag mask via ballot
  const u32 myflag = amflag[b * 32 + l31];
  const u32 fmask = (u32)__ballot(myflag != 0u);

  const u16* kbase = qk + (size_t)(b * SLEN) * LDQK + DMODEL + h * DHEAD;
  const u16* vtbase = vt + (size_t)(h * DHEAD) * VSTRIDE + b * SLEN;

#define STAGE(kt, buf)                                                              \
  {                                                                                 \
    _Pragma("unroll")                                                               \
    for (int p = 0; p < 2; ++p) {                                                   \
      const int idx = p * 256 + t;                                                  \
      const int row = idx >> 3;                                                     \
      const int blk = idx & 7;                                                      \
      const int sb = blk ^ (row & 7);                                               \
      gload_lds16(kbase + (size_t)((kt) * 64 + row) * LDQK + sb * 8,                \
                  &Ks[buf][idx * 8]);                                               \
    }                                                                               \
    _Pragma("unroll")                                                               \
    for (int p = 0; p < 2; ++p) {                                                   \
      const int idx = p * 256 + t;                                                  \
      const int dh = idx >> 3;                                                      \
      const int blk = idx & 7;                                                      \
      const int sb = blk ^ (dh & 7);                                                \
      gload_lds16(vtbase + (size_t)dh * VSTRIDE + (kt) * 64 + sb * 8,               \
                  &Vs[buf][idx * 8]);                                               \
    }                                                                               \
  }

  // One KV-tile body. BUF compile-time; stages tile kt+2 into (BUF+2)&3.
  // Ends with counted vmcnt (tile kt+1 landed; kt+2's 4 loads stay in flight)
  // + raw s_barrier (no full drain).
#define TILE_BODY(BUF, kt)                                                          \
  {                                                                                 \
    if ((kt) + 2 < SLEN / 64) STAGE((kt) + 2, ((BUF) + 2) & 3);                     \
    f32x16 sA, sB;                                                                  \
    _Pragma("unroll")                                                               \
    for (int r = 0; r < 16; ++r) { sA[r] = 0.f; sB[r] = 0.f; }                      \
    __builtin_amdgcn_s_setprio(1);                                                  \
    _Pragma("unroll")                                                               \
    for (int f = 0; f < 4; ++f) {                                                   \
      const int c = 2 * f + hi;                                                     \
      s16x8 kA = *(const s16x8*)&Ks[BUF][l31 * 64 + ((c ^ sw) & 7) * 8];            \
      s16x8 kB = *(const s16x8*)&Ks[BUF][(32 + l31) * 64 + ((c ^ sw) & 7) * 8];     \
      sA = __builtin_amdgcn_mfma_f32_32x32x16_bf16(kA, qf[f], sA, 0, 0, 0);         \
      sB = __builtin_amdgcn_mfma_f32_32x32x16_bf16(kB, qf[f], sB, 0, 0, 0);         \
    }                                                                               \
    __builtin_amdgcn_s_setprio(0);                                                  \
    const int kv0 = (kt) * 64;                                                      \
    if (fmask & (1u << (kt))) {                                                     \
      _Pragma("unroll")                                                             \
      for (int r = 0; r < 16; ++r) {                                                \
        const int rid = (r & 3) + ((r >> 2) << 3) + hi4;                            \
        sA[r] += am[b * SLEN + kv0 + rid];                                          \
        sB[r] += am[b * SLEN + kv0 + 32 + rid];                                     \
      }                                                                             \
    }                                                                               \
    float pA_[16], pB_[16];                                                         \
    _Pragma("unroll")                                                               \
    for (int r = 0; r < 16; ++r) {                                                  \
      pA_[r] = __builtin_amdgcn_exp2f(sA[r]);                                       \
      pB_[r] = __builtin_amdgcn_exp2f(sB[r]);                                       \
    }                                                                               \
    float s8[8];                                                                    \
    _Pragma("unroll")                                                               \
    for (int i = 0; i < 8; ++i)                                                     \
      s8[i] = (pA_[2 * i] + pA_[2 * i + 1]) + (pB_[2 * i] + pB_[2 * i + 1]);        \
    _Pragma("unroll")                                                               \
    for (int i = 0; i < 4; ++i) s8[i] += s8[i + 4];                                 \
    s8[0] += s8[2]; s8[1] += s8[3];                                                 \
    lsum += s8[0] + s8[1];                                                          \
    s16x8 pa0 = make_pa(pA_);                                                       \
    s16x8 pa1 = make_pa(pA_ + 8);                                                   \
    s16x8 pa2 = make_pa(pB_);                                                       \
    s16x8 pa3 = make_pa(pB_ + 8);                                                   \
    __builtin_amdgcn_s_setprio(1);                                                  \
    _Pragma("unroll")                                                               \
    for (int s = 0; s < 4; ++s) {                                                   \
      const int c = 2 * s + hi;                                                     \
      s16x8 vA = *(const s16x8*)&Vs[BUF][l31 * 64 + ((c ^ sw) & 7) * 8];            \
      s16x8 vB = *(const s16x8*)&Vs[BUF][(32 + l31) * 64 + ((c ^ sw) & 7) * 8];     \
      const s16x8 pas = (s == 0) ? pa0 : (s == 1) ? pa1 : (s == 2) ? pa2 : pa3;     \
      oA = __builtin_amdgcn_mfma_f32_32x32x16_bf16(pas, vA, oA, 0, 0, 0);           \
      oB = __builtin_amdgcn_mfma_f32_32x32x16_bf16(pas, vB, oB, 0, 0, 0);           \
    }                                                                               \
    __builtin_amdgcn_s_setprio(0);                                                  \
    if ((kt) + 2 < SLEN / 64) {                                                     \
      asm volatile("s_waitcnt vmcnt(4)" ::: "memory");                              \
    } else if ((kt) + 1 < SLEN / 64) {                                              \
      asm volatile("s_waitcnt vmcnt(0)" ::: "memory");                              \
    }                                                                               \
    __builtin_amdgcn_s_barrier();                                                   \
  }

  f32x16 oA, oB;
#pragma unroll
  for (int r = 0; r < 16; ++r) { oA[r] = 0.f; oB[r] = 0.f; }
  float lsum = 0.f;

  // prologue: stage tiles 0 and 1; wait for tile 0 only (tile 1 stays in flight)
  STAGE(0, 0);
  STAGE(1, 1);
  asm volatile("s_waitcnt vmcnt(4)" ::: "memory");
  __builtin_amdgcn_s_barrier();

  for (int kt = 0; kt < SLEN / 64; kt += 4) {
    TILE_BODY(0, kt);
    TILE_BODY(1, kt + 1);
    TILE_BODY(2, kt + 2);
    TILE_BODY(3, kt + 3);
  }

  // epilogue: finish lsum (one cross-half reduce), O/lsum + x -> out
  lsum += __shfl_xor(lsum, 32);
  bcastS[w][l31] = 1.0f / lsum;
  const size_t rowoff = (size_t)(b * SLEN + q0) * DMODEL + h * DHEAD + l31;
  float* outp = out + rowoff;
  const float* xp = x + rowoff;
#pragma unroll
  for (int r = 0; r < 16; ++r) {
    const int rid = (r & 3) + ((r >> 2) << 3) + hi4;
    const float rv = bcastS[w][rid];
    outp[(size_t)rid * DMODEL] = oA[r] * rv + xp[(size_t)rid * DMODEL];
    outp[(size_t)rid * DMODEL + 32] = oB[r] * rv + xp[(size_t)rid * DMODEL + 32];
  }
#undef TILE_BODY
#undef STAGE
}

extern "C" void kernel_launch(void* const* d_in, const int* in_sizes, int n_in,
                              void* d_out, int out_size, void* d_ws, size_t ws_size,
                              hipStream_t stream) {
  const float* x    = (const float*)d_in[0];
  const float* mask = (const float*)d_in[1];
  const float* Wq   = (const float*)d_in[2];
  const float* bq   = (const float*)d_in[3];
  const float* Wk   = (const float*)d_in[4];
  const float* bk   = (const float*)d_in[5];
  const float* Wv   = (const float*)d_in[6];
  const float* bv   = (const float*)d_in[7];
  const float* Wo   = (const float*)d_in[8];
  const float* bo   = (const float*)d_in[9];
  const float* g1   = (const float*)d_in[10];
  const float* b1   = (const float*)d_in[11];
  const float* g2   = (const float*)d_in[12];
  const float* b2   = (const float*)d_in[13];
  float* out = (float*)d_out;
  char* ws = (char*)d_ws;

  u16*   h_bf  = (u16*)(ws + 0);                       // 8 MB  (reused as h2 later)
  u16*   Wqkv  = (u16*)(ws + ((size_t)8 << 20));       // 6 MB
  u16*   Wob   = (u16*)(ws + ((size_t)14 << 20));      // 2 MB
  float* biasq = (float*)(ws + ((size_t)16 << 20));    // 12 KB
  float* amv   = (float*)(ws + ((size_t)16 << 20) + (64 << 10));  // 16 KB
  u32*   amfl  = (u32*)(ws + ((size_t)16 << 20) + (128 << 10));   // 256 B
  u16*   qkbuf = (u16*)(ws + ((size_t)17 << 20));      // 16 MB
  u16*   vT2   = (u16*)(ws + ((size_t)33 << 20));      // 8 MB
  float* resb  = (float*)(ws + ((size_t)41 << 20));    // 16 MB: attn-out + x (residual)
  u16*   h2_bf = (u16*)(ws + 0);                       // overlays dead h_bf

  prep_kernel<<<8192, 256, 0, stream>>>(x, Wq, Wk, Wv, Wo, bq, bk, bv, mask, g1, b1,
                                        Wqkv, Wob, biasq, amv, amfl, h_bf);
  qkv_gemm_kernel<<<768, 256, 0, stream>>>(h_bf, Wqkv, biasq, qkbuf, vT2);
  attn_kernel<<<512, 256, 0, stream>>>(qkbuf, vT2, amv, amfl, x, resb);
  ln_kernel<<<4096, 256, 0, stream>>>(resb, g2, b2, h2_bf);
  out_gemm_kernel<<<256, 256, 0, stream>>>(h2_bf, Wob, bo, resb, out);
}

// Round 19
// 139.382 us; speedup vs baseline: 1.1508x; 1.1508x over previous
//
#include <hip/hip_runtime.h>
#include <hip/hip_bf16.h>

typedef unsigned short u16;
typedef unsigned int u32;
typedef __attribute__((ext_vector_type(8))) short s16x8;
typedef __attribute__((ext_vector_type(4))) float f32x4;
typedef __attribute__((ext_vector_type(16))) float f32x16;
typedef __attribute__((ext_vector_type(4))) u16 u16x4;

#define SLEN 2048
#define DMODEL 1024
#define NHEAD 16
#define DHEAD 64
#define LDQK 2048
#define VSTRIDE 4096
#define LOG2E 1.4426950408889634f

__device__ __forceinline__ u16 f2bf(float f) {
  union { __hip_bfloat16 h; u16 u; } c;
  c.h = __float2bfloat16(f);
  return c.u;
}

__device__ __forceinline__ u32 pk2(float a, float b) {
  union { __hip_bfloat162 h2; u32 u; } c;
  float2 f2; f2.x = a; f2.y = b;
  c.h2 = __float22bfloat162_rn(f2);
  return c.u;
}

__device__ __forceinline__ void gload_lds16(const u16* gsrc, u16* lds) {
  __builtin_amdgcn_global_load_lds((const __attribute__((address_space(1))) void*)gsrc,
                                   (__attribute__((address_space(3))) void*)lds, 16, 0, 0);
}

// Build PV A-fragment from 8 P values. v_permlane32_swap_b32 D,S swaps
// D[32:63] <-> S[0:31]. swap(A0,A2)/swap(A1,A3) reproduces the r4-verified
// shfl mapping in 2 ops (r14-verified: absmax unchanged, attn -5us).
__device__ __forceinline__ s16x8 make_pa(const float* p) {
  u32 A0 = pk2(p[0], p[1]), A1 = pk2(p[2], p[3]);
  u32 A2 = pk2(p[4], p[5]), A3 = pk2(p[6], p[7]);
  asm("v_permlane32_swap_b32 %0, %1" : "+v"(A0), "+v"(A2));
  asm("v_permlane32_swap_b32 %0, %1" : "+v"(A1), "+v"(A3));
  union { u32 w[4]; s16x8 v; } pw;
  pw.w[0] = A0; pw.w[1] = A1; pw.w[2] = A2; pw.w[3] = A3;
  return pw.v;
}

// ---------------- LayerNorm body (shared) ----------------
__device__ __forceinline__ void ln_body(
    int row, int t, const float* __restrict__ xa,
    const float* __restrict__ g, const float* __restrict__ bb,
    u16* __restrict__ outb) {
  const size_t base = (size_t)row * DMODEL;
  float4 v = *((const float4*)(xa + base) + t);
  float s1 = v.x + v.y + v.z + v.w;
  float s2 = v.x * v.x + v.y * v.y + v.z * v.z + v.w * v.w;
#pragma unroll
  for (int d = 1; d < 64; d <<= 1) { s1 += __shfl_xor(s1, d); s2 += __shfl_xor(s2, d); }
  __shared__ float red[8];
  if ((t & 63) == 0) { red[(t >> 6) * 2] = s1; red[(t >> 6) * 2 + 1] = s2; }
  __syncthreads();
  s1 = red[0] + red[2] + red[4] + red[6];
  s2 = red[1] + red[3] + red[5] + red[7];
  const float mu = s1 * (1.0f / 1024.0f);
  const float var = s2 * (1.0f / 1024.0f) - mu * mu;
  const float rs = rsqrtf(var + 1e-6f);
  const int c = t * 4;
  float o0 = (v.x - mu) * rs * g[c + 0] + bb[c + 0];
  float o1 = (v.y - mu) * rs * g[c + 1] + bb[c + 1];
  float o2 = (v.z - mu) * rs * g[c + 2] + bb[c + 2];
  float o3 = (v.w - mu) * rs * g[c + 3] + bb[c + 3];
  u16x4 o = { f2bf(o0), f2bf(o1), f2bf(o2), f2bf(o3) };
  *((u16x4*)(outb + base) + t) = o;
}

// ---------------- fused: weight convert (blocks 0..4095) + LN1 (blocks 4096..8191) ----------------
__global__ __launch_bounds__(256) void prep_kernel(
    const float* __restrict__ x,
    const float* __restrict__ Wq, const float* __restrict__ Wk, const float* __restrict__ Wv,
    const float* __restrict__ Wo, const float* __restrict__ bq, const float* __restrict__ bk,
    const float* __restrict__ bv, const float* __restrict__ mask,
    const float* __restrict__ g1, const float* __restrict__ b1,
    u16* __restrict__ Wqkv, u16* __restrict__ Wob, float* __restrict__ bias_qkv,
    float* __restrict__ am, u32* __restrict__ amflag, u16* __restrict__ h_bf) {
  const int bid = blockIdx.x;
  if (bid >= 4096) {
    ln_body(bid - 4096, threadIdx.x, x, g1, b1, h_bf);
    return;
  }
  const int t = bid * 256 + threadIdx.x;
  float4 v;
  u16* dst;
  if (t < 786432) {
    const int idx = t * 4;
    const int sec = idx >> 20;
    const int off = idx & 1048575;
    const float* src = (sec == 0) ? Wq : (sec == 1) ? Wk : Wv;
    v = *(const float4*)(src + off);
    dst = Wqkv + idx;
  } else {
    const int idx = (t - 786432) * 4;
    v = *(const float4*)(Wo + idx);
    dst = Wob + idx;
  }
  u16x4 o = { f2bf(v.x), f2bf(v.y), f2bf(v.z), f2bf(v.w) };
  *(u16x4*)dst = o;
  if (t < 768) {
    const int idx = t * 4;
    const int sec = idx >> 10;
    const int off = idx & 1023;
    const float* src = (sec == 0) ? bq : (sec == 1) ? bk : bv;
    *(float4*)(bias_qkv + idx) = *(const float4*)(src + off);
  }
  if (t < 1024) {
    const int idx = t * 4;
    float4 mk = *(const float4*)(mask + idx);
    const float C = -1e30f * LOG2E;
    float4 o2 = { (1.f - mk.x) * C, (1.f - mk.y) * C,
                  (1.f - mk.z) * C, (1.f - mk.w) * C };
    *(float4*)(am + idx) = o2;
  }
  if (t < 64) {
    const int bb = t >> 5, tile = t & 31;
    u32 fl = 0;
    for (int j = 0; j < 64; ++j)
      fl |= (mask[bb * SLEN + tile * 64 + j] != 1.0f) ? 1u : 0u;
    amflag[t] = fl;
  }
}

// ---------------- plain LN kernel (post-attention) ----------------
__global__ __launch_bounds__(256) void ln_kernel(
    const float* __restrict__ xa, const float* __restrict__ g,
    const float* __restrict__ bb, u16* __restrict__ outb) {
  ln_body(blockIdx.x, threadIdx.x, xa, g, bb, outb);
}

// ---------------- GEMM core (r13-proven): BK=64, single-stage, 32 MFMAs/barrier ----------------
__device__ __forceinline__ void gemm_core(
    const u16* __restrict__ A, const u16* __restrict__ B,
    const float* __restrict__ bias, const float* __restrict__ res,
    u16* __restrict__ outb, float* __restrict__ outf,
    int M, int N, int K, int m0, int n0, int mode,
    u16* As, u16* Bs) {
  const int t = threadIdx.x;
  const int l = t & 63, w = t >> 6, lr = l & 15, lg = l >> 4;
  const int wm = w >> 1, wn = w & 1;

  const f32x4 z4 = {0.f, 0.f, 0.f, 0.f};
  f32x4 acc[4][4];
#pragma unroll
  for (int i = 0; i < 4; ++i)
#pragma unroll
    for (int j = 0; j < 4; ++j) acc[i][j] = z4;

  for (int kt = 0; kt < K; kt += 64) {
#pragma unroll
    for (int p = 0; p < 4; ++p) {
      const int idx = p * 256 + t;
      const int row = idx >> 3;
      const int blk = idx & 7;
      const int sb = blk ^ (row & 7);
      gload_lds16(A + (size_t)(m0 + row) * K + kt + sb * 8, &As[idx * 8]);
      gload_lds16(B + (size_t)(n0 + row) * K + kt + sb * 8, &Bs[idx * 8]);
    }
    asm volatile("s_waitcnt vmcnt(0)" ::: "memory");
    __syncthreads();

#pragma unroll
    for (int ks = 0; ks < 2; ++ks) {
      s16x8 af[4], bfr[4];
#pragma unroll
      for (int mi = 0; mi < 4; ++mi) {
        const int row = wm * 64 + mi * 16 + lr;
        af[mi] = *(const s16x8*)&As[row * 64 + (((ks * 4 + lg) ^ (row & 7)) & 7) * 8];
      }
#pragma unroll
      for (int ni = 0; ni < 4; ++ni) {
        const int row = wn * 64 + ni * 16 + lr;
        bfr[ni] = *(const s16x8*)&Bs[row * 64 + (((ks * 4 + lg) ^ (row & 7)) & 7) * 8];
      }
#pragma unroll
      for (int mi = 0; mi < 4; ++mi)
#pragma unroll
        for (int ni = 0; ni < 4; ++ni)
          acc[mi][ni] = __builtin_amdgcn_mfma_f32_16x16x32_bf16(af[mi], bfr[ni], acc[mi][ni], 0, 0, 0);
    }
    __syncthreads();
  }

#pragma unroll
  for (int mi = 0; mi < 4; ++mi)
#pragma unroll
    for (int ni = 0; ni < 4; ++ni) {
      const int col = n0 + wn * 64 + ni * 16 + lr;
#pragma unroll
      for (int r = 0; r < 4; ++r) {
        const int rowb = m0 + wm * 64 + mi * 16 + lg * 4 + r;
        float vv = acc[mi][ni][r];
        if (mode == 2) {
          vv += bias[rowb];
          outb[(size_t)rowb * N + col] = f2bf(vv);
        } else if (mode == 0) {
          vv += bias[col];
          if (col < 1024) vv *= 0.125f * LOG2E;
          outb[(size_t)rowb * N + col] = f2bf(vv);
        } else {
          vv += bias[col] + res[(size_t)rowb * N + col];
          outf[(size_t)rowb * N + col] = vv;
        }
      }
    }
}

// fused QK-proj (lids 0..511) + V^T-proj (lids 512..767), XCD-chunked
__global__ __launch_bounds__(256) void qkv_gemm_kernel(
    const u16* __restrict__ h_bf, const u16* __restrict__ Wqkv,
    const float* __restrict__ biasq, u16* __restrict__ qkbuf, u16* __restrict__ vT) {
  __shared__ __align__(16) u16 As[128 * 64];
  __shared__ __align__(16) u16 Bs[128 * 64];
  const int bid = blockIdx.x;
  const int lid = (bid & 7) * 96 + (bid >> 3);   // 768 = 8 * 96, bijective
  if (lid < 512) {
    gemm_core(h_bf, Wqkv, biasq, nullptr, qkbuf, nullptr,
              4096, 2048, 1024, (lid & 31) * 128, (lid >> 5) * 128, 0, As, Bs);
  } else {
    const int id = lid - 512;
    gemm_core(Wqkv + (size_t)2048 * 1024, h_bf, biasq + 2048, nullptr, vT, nullptr,
              1024, 4096, 1024, (id & 7) * 128, (id >> 3) * 128, 2, As, Bs);
  }
}

// output projection with fused residual, XCD-chunked (grid 256)
__global__ __launch_bounds__(256) void out_gemm_kernel(
    const u16* __restrict__ h2, const u16* __restrict__ Wob,
    const float* __restrict__ bo, const float* __restrict__ res,
    float* __restrict__ outf) {
  __shared__ __align__(16) u16 As[128 * 64];
  __shared__ __align__(16) u16 Bs[128 * 64];
  const int bid = blockIdx.x;
  const int lid = (bid & 7) * 32 + (bid >> 3);   // 256 = 8 * 32, bijective
  gemm_core(h2, Wob, bo, res, nullptr, outf,
            4096, 1024, 1024, (lid & 31) * 128, (lid >> 5) * 128, 1, As, Bs);
}

// ---------------- flash attention, fixed-max softmax; epilogue adds x (residual) ----------------
// grid: 512 blocks x 256 thr (4 waves); wave owns 32 q rows; KV tile = 64.
// kt-loop manually unrolled x2 so each body has a compile-time buffer index
// and all LDS addresses are loop-invariant (hoisted once).
__global__ __launch_bounds__(256) void attn_kernel(
    const u16* __restrict__ qk, const u16* __restrict__ vt,
    const float* __restrict__ am, const u32* __restrict__ amflag,
    const float* __restrict__ x, float* __restrict__ out) {
  const int did = blockIdx.x;
  const int lid = (did & 7) * 64 + (did >> 3);   // XCD-chunked (512 % 8 == 0)
  const int qb = lid & 15;
  const int h = (lid >> 4) & 15;
  const int b = lid >> 8;

  const int t = threadIdx.x;
  const int l = t & 63, w = t >> 6;
  const int l31 = l & 31;
  const int hi = l >> 5;
  const int hi4 = hi * 4;
  const int sw = l31 & 7;

  __shared__ __align__(16) u16 Ks[2][64 * 64];
  __shared__ __align__(16) u16 Vs[2][64 * 64];
  __shared__ float bcastS[4][32];

  const int q0 = qb * 128 + w * 32;

  const u16* qrow = qk + (size_t)(b * SLEN + q0 + l31) * LDQK + h * DHEAD + hi * 8;
  s16x8 qf[4];
#pragma unroll
  for (int f = 0; f < 4; ++f) qf[f] = *(const s16x8*)(qrow + f * 16);

  // per-wave 32-bit tile-flag mask via ballot
  const u32 myflag = amflag[b * 32 + l31];
  const u32 fmask = (u32)__ballot(myflag != 0u);

  const u16* kbase = qk + (size_t)(b * SLEN) * LDQK + DMODEL + h * DHEAD;
  const u16* vtbase = vt + (size_t)(h * DHEAD) * VSTRIDE + b * SLEN;

#define STAGE(kt, buf)                                                              \
  {                                                                                 \
    _Pragma("unroll")                                                               \
    for (int p = 0; p < 2; ++p) {                                                   \
      const int idx = p * 256 + t;                                                  \
      const int row = idx >> 3;                                                     \
      const int blk = idx & 7;                                                      \
      const int sb = blk ^ (row & 7);                                               \
      gload_lds16(kbase + (size_t)((kt) * 64 + row) * LDQK + sb * 8,                \
                  &Ks[buf][idx * 8]);                                               \
    }                                                                               \
    _Pragma("unroll")                                                               \
    for (int p = 0; p < 2; ++p) {                                                   \
      const int idx = p * 256 + t;                                                  \
      const int dh = idx >> 3;                                                      \
      const int blk = idx & 7;                                                      \
      const int sb = blk ^ (dh & 7);                                                \
      gload_lds16(vtbase + (size_t)dh * VSTRIDE + (kt) * 64 + sb * 8,               \
                  &Vs[buf][idx * 8]);                                               \
    }                                                                               \
  }

  // One KV-tile body with compile-time LDS buffer index BUF.
#define TILE_BODY(BUF, kt)                                                          \
  {                                                                                 \
    if ((kt) + 1 < SLEN / 64) STAGE((kt) + 1, 1 - (BUF));                           \
    f32x16 sA, sB;                                                                  \
    _Pragma("unroll")                                                               \
    for (int r = 0; r < 16; ++r) { sA[r] = 0.f; sB[r] = 0.f; }                      \
    __builtin_amdgcn_s_setprio(1);                                                  \
    _Pragma("unroll")                                                               \
    for (int f = 0; f < 4; ++f) {                                                   \
      const int c = 2 * f + hi;                                                     \
      s16x8 kA = *(const s16x8*)&Ks[BUF][l31 * 64 + ((c ^ sw) & 7) * 8];            \
      s16x8 kB = *(const s16x8*)&Ks[BUF][(32 + l31) * 64 + ((c ^ sw) & 7) * 8];     \
      sA = __builtin_amdgcn_mfma_f32_32x32x16_bf16(kA, qf[f], sA, 0, 0, 0);         \
      sB = __builtin_amdgcn_mfma_f32_32x32x16_bf16(kB, qf[f], sB, 0, 0, 0);         \
    }                                                                               \
    __builtin_amdgcn_s_setprio(0);                                                  \
    const int kv0 = (kt) * 64;                                                      \
    if (fmask & (1u << (kt))) {                                                     \
      _Pragma("unroll")                                                             \
      for (int r = 0; r < 16; ++r) {                                                \
        const int rid = (r & 3) + ((r >> 2) << 3) + hi4;                            \
        sA[r] += am[b * SLEN + kv0 + rid];                                          \
        sB[r] += am[b * SLEN + kv0 + 32 + rid];                                     \
      }                                                                             \
    }                                                                               \
    float pA_[16], pB_[16];                                                         \
    _Pragma("unroll")                                                               \
    for (int r = 0; r < 16; ++r) {                                                  \
      pA_[r] = __builtin_amdgcn_exp2f(sA[r]);                                       \
      pB_[r] = __builtin_amdgcn_exp2f(sB[r]);                                       \
    }                                                                               \
    float s8[8];                                                                    \
    _Pragma("unroll")                                                               \
    for (int i = 0; i < 8; ++i)                                                     \
      s8[i] = (pA_[2 * i] + pA_[2 * i + 1]) + (pB_[2 * i] + pB_[2 * i + 1]);        \
    _Pragma("unroll")                                                               \
    for (int i = 0; i < 4; ++i) s8[i] += s8[i + 4];                                 \
    s8[0] += s8[2]; s8[1] += s8[3];                                                 \
    lsum += s8[0] + s8[1];                                                          \
    s16x8 pa0 = make_pa(pA_);                                                       \
    s16x8 pa1 = make_pa(pA_ + 8);                                                   \
    s16x8 pa2 = make_pa(pB_);                                                       \
    s16x8 pa3 = make_pa(pB_ + 8);                                                   \
    __builtin_amdgcn_s_setprio(1);                                                  \
    _Pragma("unroll")                                                               \
    for (int s = 0; s < 4; ++s) {                                                   \
      const int c = 2 * s + hi;                                                     \
      s16x8 vA = *(const s16x8*)&Vs[BUF][l31 * 64 + ((c ^ sw) & 7) * 8];            \
      s16x8 vB = *(const s16x8*)&Vs[BUF][(32 + l31) * 64 + ((c ^ sw) & 7) * 8];     \
      const s16x8 pas = (s == 0) ? pa0 : (s == 1) ? pa1 : (s == 2) ? pa2 : pa3;     \
      oA = __builtin_amdgcn_mfma_f32_32x32x16_bf16(pas, vA, oA, 0, 0, 0);           \
      oB = __builtin_amdgcn_mfma_f32_32x32x16_bf16(pas, vB, oB, 0, 0, 0);           \
    }                                                                               \
    __builtin_amdgcn_s_setprio(0);                                                  \
    asm volatile("s_waitcnt vmcnt(0)" ::: "memory");                                \
    __syncthreads();                                                                \
  }

  f32x16 oA, oB;
#pragma unroll
  for (int r = 0; r < 16; ++r) { oA[r] = 0.f; oB[r] = 0.f; }
  float lsum = 0.f;

  STAGE(0, 0);
  asm volatile("s_waitcnt vmcnt(0)" ::: "memory");
  __syncthreads();

  for (int kt = 0; kt < SLEN / 64; kt += 2) {
    TILE_BODY(0, kt);
    TILE_BODY(1, kt + 1);
  }

  // epilogue: finish lsum (one cross-half reduce), O/lsum + x -> out
  lsum += __shfl_xor(lsum, 32);
  bcastS[w][l31] = 1.0f / lsum;
  const size_t rowoff = (size_t)(b * SLEN + q0) * DMODEL + h * DHEAD + l31;
  float* outp = out + rowoff;
  const float* xp = x + rowoff;
#pragma unroll
  for (int r = 0; r < 16; ++r) {
    const int rid = (r & 3) + ((r >> 2) << 3) + hi4;
    const float rv = bcastS[w][rid];
    outp[(size_t)rid * DMODEL] = oA[r] * rv + xp[(size_t)rid * DMODEL];
    outp[(size_t)rid * DMODEL + 32] = oB[r] * rv + xp[(size_t)rid * DMODEL + 32];
  }
#undef TILE_BODY
#undef STAGE
}

extern "C" void kernel_launch(void* const* d_in, const int* in_sizes, int n_in,
                              void* d_out, int out_size, void* d_ws, size_t ws_size,
                              hipStream_t stream) {
  const float* x    = (const float*)d_in[0];
  const float* mask = (const float*)d_in[1];
  const float* Wq   = (const float*)d_in[2];
  const float* bq   = (const float*)d_in[3];
  const float* Wk   = (const float*)d_in[4];
  const float* bk   = (const float*)d_in[5];
  const float* Wv   = (const float*)d_in[6];
  const float* bv   = (const float*)d_in[7];
  const float* Wo   = (const float*)d_in[8];
  const float* bo   = (const float*)d_in[9];
  const float* g1   = (const float*)d_in[10];
  const float* b1   = (const float*)d_in[11];
  const float* g2   = (const float*)d_in[12];
  const float* b2   = (const float*)d_in[13];
  float* out = (float*)d_out;
  char* ws = (char*)d_ws;

  u16*   h_bf  = (u16*)(ws + 0);                       // 8 MB  (reused as h2 later)
  u16*   Wqkv  = (u16*)(ws + ((size_t)8 << 20));       // 6 MB
  u16*   Wob   = (u16*)(ws + ((size_t)14 << 20));      // 2 MB
  float* biasq = (float*)(ws + ((size_t)16 << 20));    // 12 KB
  float* amv   = (float*)(ws + ((size_t)16 << 20) + (64 << 10));  // 16 KB
  u32*   amfl  = (u32*)(ws + ((size_t)16 << 20) + (128 << 10));   // 256 B
  u16*   qkbuf = (u16*)(ws + ((size_t)17 << 20));      // 16 MB
  u16*   vT2   = (u16*)(ws + ((size_t)33 << 20));      // 8 MB
  float* resb  = (float*)(ws + ((size_t)41 << 20));    // 16 MB: attn-out + x (residual)
  u16*   h2_bf = (u16*)(ws + 0);                       // overlays dead h_bf

  prep_kernel<<<8192, 256, 0, stream>>>(x, Wq, Wk, Wv, Wo, bq, bk, bv, mask, g1, b1,
                                        Wqkv, Wob, biasq, amv, amfl, h_bf);
  qkv_gemm_kernel<<<768, 256, 0, stream>>>(h_bf, Wqkv, biasq, qkbuf, vT2);
  attn_kernel<<<512, 256, 0, stream>>>(qkbuf, vT2, amv, amfl, x, resb);
  ln_kernel<<<4096, 256, 0, stream>>>(resb, g2, b2, h2_bf);
  out_gemm_kernel<<<256, 256, 0, stream>>>(h2_bf, Wob, bo, resb, out);
}